// Round 9
// baseline (26.296 us; speedup 1.0000x reference)
//
#include <hip/hip_runtime.h>

// anchors[MASK] / stride:  [[1.25,1.625],[2.0,3.75],[4.125,2.875]]
__constant__ float c_aw[3] = {1.25f, 2.0f, 4.125f};
__constant__ float c_ah[3] = {1.625f, 3.75f, 2.875f};

#define LOG2E 1.4426950408889634f
#define LN2   0.6931471805599453f
#define NBLK  2048
#define MAXG  256

// softplus(v) = log(1+e^v), via native v_exp_f32 / v_log_f32 (both ~1 ulp)
__device__ __forceinline__ float softplus_fast(float v) {
    float a = fabsf(v);
    float e = __builtin_amdgcn_exp2f(-a * LOG2E);     // e^{-|v|} in [0,1]
    float l = __builtin_amdgcn_logf(1.0f + e) * LN2;  // log1p(e), arg in [1,2]
    return fmaxf(v, 0.0f) + l;
}

// BCE(sigmoid(v), t) with torch-style clamp(log, -100)
__device__ __forceinline__ float bce_logit(float v, float t) {
    float l1p = fmaxf(-softplus_fast(v),  -100.0f);  // log(1-p)
    float lp  = fmaxf(-softplus_fast(-v), -100.0f);  // log(p)
    return -(t * lp + (1.0f - t) * l1p);
}

__device__ __forceinline__ float iou_box(float ax0, float ay0, float ax1, float ay1,
                                         float bx0, float by0, float bx1, float by1) {
    float ltx = fmaxf(ax0, bx0), lty = fmaxf(ay0, by0);
    float rbx = fminf(ax1, bx1), rby = fminf(ay1, by1);
    float iw = fmaxf(rbx - ltx, 0.0f), ih = fmaxf(rby - lty, 0.0f);
    float inter = iw * ih;
    float a1 = (ax1 - ax0) * (ay1 - ay0);
    float a2 = (bx1 - bx0) * (by1 - by0);
    return inter / (a1 + a2 - inter);
}

// ws layout (floats) — only per-block partial slots, all written
// unconditionally every call (poison-safe, no memset, no atomics, no fences):
// [0 .. NBLK)            per-block cls partials
// [NBLK .. 2*NBLK)       per-block obj partials
// [2*NBLK .. +sblk*11)   per-sparse-block partials (11 each)

// K1: dense grid-stride reduce (all blocks) + sparse gt/anchor section
// (blocks < sblk). Dense inner loop in log2 domain: s = min(log2(1+2^(v*log2e)),
// 100*log2e); *ln2 deferred to the block epilogue. Classification on the cell
// phase r = (4i) % 85 with compile-time thresholds per unrolled j:
//   f_j < 5  <=>  r < 5-j || r >= 85-j      (skip-set; subtracted from total)
//   f_j == 4 <=>  r == 4-j                  (objectness)
// r advances by (4*NBLK*256) % 85 == 32 per trip (no per-trip integer mod).
__global__ void __launch_bounds__(256) yolo_main(const float4* __restrict__ p4, int n4,
                                                 const float* __restrict__ pred,
                                                 const float* __restrict__ gt, int G,
                                                 float* __restrict__ cls_part,
                                                 float* __restrict__ obj_part,
                                                 float* __restrict__ sp_part, int sblk) {
    int tid = threadIdx.x;
    int lane = tid & 63;
    int wave = tid >> 6;

    // ---------------- dense pass (all blocks) ----------------
    float atot = 0.0f, askip = 0.0f, aobj = 0.0f;     // log2 units
    const float C100 = 100.0f * LOG2E;
    int i = blockIdx.x * 256 + tid;
    int r = (i * 4) % 85;
    for (; i < n4; i += NBLK * 256) {
        float4 v = p4[i];
        float vs[4] = {v.x, v.y, v.z, v.w};
        float s[4];
#pragma unroll
        for (int j = 0; j < 4; ++j) {
            float t = __builtin_amdgcn_exp2f(vs[j] * LOG2E);
            s[j] = fminf(__builtin_amdgcn_logf(1.0f + t), C100);
            atot += s[j];
        }
        // skip-set (f<5) and obj (f==4) per unrolled j; constants fold.
        askip += (r < 5) ? s[0] : 0.0f;
        askip += (r < 4 || r >= 84) ? s[1] : 0.0f;
        askip += (r < 3 || r >= 83) ? s[2] : 0.0f;
        askip += (r < 2 || r >= 82) ? s[3] : 0.0f;
        aobj  += (r == 4) ? s[0] : 0.0f;
        aobj  += (r == 3) ? s[1] : 0.0f;
        aobj  += (r == 2) ? s[2] : 0.0f;
        aobj  += (r == 1) ? s[3] : 0.0f;
        r += 32;                       // (4*NBLK*256) % 85
        r = (r >= 85) ? r - 85 : r;
    }
    float acls = (atot - askip) * LN2;          // back to natural log
    float aob  = aobj * LN2;
#pragma unroll
    for (int off = 32; off > 0; off >>= 1) {
        acls += __shfl_down(acls, off);
        aob  += __shfl_down(aob, off);
    }
    __shared__ float rc[4], ro[4];
    if (lane == 0) { rc[wave] = acls; ro[wave] = aob; }
    __syncthreads();
    if (tid == 0) {
        cls_part[blockIdx.x] = rc[0] + rc[1] + rc[2] + rc[3];
        obj_part[blockIdx.x] = ro[0] + ro[1] + ro[2] + ro[3];
    }

    // ---------------- sparse pass (blocks < sblk) ----------------
    if (blockIdx.x < (unsigned)sblk) {
        __shared__ float s_cx[MAXG], s_cy[MAXG], s_gw[MAXG], s_gh[MAXG], s_sc[MAXG];
        __shared__ int s_ix[MAXG], s_iy[MAXG], s_bs[MAXG], s_lab[MAXG];
        __shared__ unsigned char s_m[3 * MAXG];
        __shared__ float acc[11];
        if (tid < 11) acc[tid] = 0.0f;

        for (int g = tid; g < G; g += blockDim.x) {
            float lab = gt[g * 6 + 0];
            float cx  = gt[g * 6 + 1] * 52.0f;
            float cy  = gt[g * 6 + 2] * 52.0f;
            float gw  = gt[g * 6 + 3] * 52.0f;
            float gh  = gt[g * 6 + 4] * 52.0f;
            float bn  = gt[g * 6 + 5];
            s_cx[g] = cx; s_cy[g] = cy; s_gw[g] = gw; s_gh[g] = gh;
            s_ix[g] = (int)floorf(cx); s_iy[g] = (int)floorf(cy);
            s_bs[g] = (int)bn; s_lab[g] = (int)lab;
            s_sc[g] = 2.0f - (gw * 8.0f) * (gh * 8.0f) / 173056.0f;
        }
        __syncthreads();

        for (int t = tid; t < 3 * G; t += blockDim.x) {
            int g = t / 3, a = t % 3;
            float cx = s_cx[g], cy = s_cy[g], gw = s_gw[g], gh = s_gh[g];
            float aw = c_aw[a], ah = c_ah[a];
            float iou = iou_box(cx - gw * 0.5f, cy - gh * 0.5f,
                                cx + gw * 0.5f, cy + gh * 0.5f,
                                cx - aw * 0.5f, cy - ah * 0.5f,
                                cx + aw * 0.5f, cy + ah * 0.5f);
            s_m[t] = (iou > 0.3f) ? 1 : 0;
        }
        __syncthreads();

        int t = blockIdx.x * 4 + wave;       // pair index (wave-uniform)
        bool active = (t < 3 * G) && s_m[t];
        if (active) {
            int g = t / 3, a = t % 3;
            int ix = s_ix[g], iy = s_iy[g], bs = s_bs[g], lab = s_lab[g];
            // wave-parallel "any later gt writing same cell (/same label)?"
            bool ohit = false, rhit = false;
            for (int g2 = g + 1 + lane; g2 < G; g2 += 64) {
                if (s_m[g2 * 3 + a] && s_bs[g2] == bs && s_ix[g2] == ix && s_iy[g2] == iy) {
                    ohit = true;
                    if (s_lab[g2] == lab) rhit = true;
                }
            }
            bool owner = !__any(ohit);
            bool rep   = !__any(rhit);

            if (lane == 0) {
                float cx = s_cx[g], cy = s_cy[g], gw = s_gw[g], gh = s_gh[g], sc = s_sc[g];
                float aw = c_aw[a], ah = c_ah[a];
                int base = ((bs * 3 + a) * 2704 + ix * 52 + iy) * 85;
                float v0 = pred[base + 0], v1 = pred[base + 1], v2 = pred[base + 2];
                float v3 = pred[base + 3], v4 = pred[base + 4];
                // reference quirk: predx adds the H-axis grid (iy), predy adds ix
                float px = 1.0f / (1.0f + __builtin_amdgcn_exp2f(-v0 * LOG2E)) + (float)iy;
                float py = 1.0f / (1.0f + __builtin_amdgcn_exp2f(-v1 * LOG2E)) + (float)ix;
                float pw = __builtin_amdgcn_exp2f(v2 * LOG2E) * aw;
                float ph = __builtin_amdgcn_exp2f(v3 * LOG2E) * ah;
                float pg = iou_box(cx - gw * 0.5f, cy - gh * 0.5f,
                                   cx + gw * 0.5f, cy + gh * 0.5f,
                                   px - pw * 0.5f, py - ph * 0.5f,
                                   px + pw * 0.5f, py + ph * 0.5f);
                atomicAdd(&acc[7], 1.0f);                 // nmask
                atomicAdd(&acc[6], (1.0f - pg) * sc);     // iou loss sum
                if (pg > 0.5f)  atomicAdd(&acc[8], 1.0f);
                if (pg > 0.75f) atomicAdd(&acc[9], 1.0f);
                if (owner) {  // last-write-wins owner of cell (bs,a,ix,iy)
                    float tx = cx - floorf(cx);
                    float ty = cy - floorf(cy);
                    float ow = __builtin_amdgcn_logf(gw / aw) * LN2;
                    float oh = __builtin_amdgcn_logf(gh / ah) * LN2;
                    atomicAdd(&acc[0], sc * bce_logit(v0, tx));
                    atomicAdd(&acc[1], sc * bce_logit(v1, ty));
                    float dw = v2 * sc - ow * sc;
                    float dh = v3 * sc - oh * sc;
                    atomicAdd(&acc[2], dw * dw);
                    atomicAdd(&acc[3], dh * dh);
                    atomicAdd(&acc[4], bce_logit(v4, 1.0f) - bce_logit(v4, 0.0f));
                }
                if (rep) {   // unique (cell,label) representative
                    float vc = pred[base + 5 + lab];
                    atomicAdd(&acc[5], bce_logit(vc, 1.0f) - bce_logit(vc, 0.0f));
                    atomicAdd(&acc[10], 1.0f);
                }
            }
        }
        __syncthreads();
        if (tid < 11) sp_part[blockIdx.x * 11 + tid] = acc[tid];
    }
}

// K2: sums all partials and composes the 10 outputs (1 block).
__global__ void __launch_bounds__(256) finalize_k(const float* __restrict__ cls_part,
                                                  const float* __restrict__ obj_part,
                                                  const float* __restrict__ sp_part, int sblk,
                                                  float* __restrict__ out) {
    float c = 0.0f, o = 0.0f;
    for (int i = threadIdx.x; i < NBLK; i += 256) {
        c += cls_part[i];
        o += obj_part[i];
    }
    float a[11];
#pragma unroll
    for (int k = 0; k < 11; ++k) a[k] = 0.0f;
    for (int b = threadIdx.x; b < sblk; b += 256) {
#pragma unroll
        for (int k = 0; k < 11; ++k) a[k] += sp_part[b * 11 + k];
    }
#pragma unroll
    for (int off = 32; off > 0; off >>= 1) {
        c += __shfl_down(c, off);
        o += __shfl_down(o, off);
#pragma unroll
        for (int k = 0; k < 11; ++k) a[k] += __shfl_down(a[k], off);
    }
    __shared__ float red[4][13];
    int wave = threadIdx.x >> 6, lane = threadIdx.x & 63;
    if (lane == 0) {
        red[wave][0] = c; red[wave][1] = o;
#pragma unroll
        for (int k = 0; k < 11; ++k) red[wave][2 + k] = a[k];
    }
    __syncthreads();
    if (threadIdx.x == 0) {
        float s[13];
#pragma unroll
        for (int k = 0; k < 13; ++k)
            s[k] = red[0][k] + red[1][k] + red[2][k] + red[3][k];
        float cls_base = s[0], obj_base = s[1];
        float SX = s[2], SY = s[3], SW = s[4], SH = s[5], OBJC = s[6], CLSC = s[7];
        float IOUS = s[8], NMASK = s[9], R50 = s[10], R75 = s[11], DEN = s[12];
        const float NCELL = 259584.0f;      // 32*3*52*52
        const float NCLSE = 20766720.0f;    // *80
        float lossx = SX / NCELL;
        float lossy = SY / NCELL;
        float lossw = SW / NCELL;
        float lossh = SH / NCELL;
        float lossobj = (obj_base + OBJC) / NCELL;
        float losscls = (cls_base + CLSC) / NCLSE;
        float lossiou = (NMASK > 0.0f) ? (IOUS / fmaxf(NMASK, 1.0f)) : 0.0f;
        float denom = DEN + 1e-10f;
        float r50 = R50 / denom;
        float r75 = R75 / denom;
        float loss = lossx + lossy + lossw + lossh + lossobj + losscls + lossiou;
        out[0] = loss;  out[1] = lossx;   out[2] = lossy;   out[3] = lossw; out[4] = lossh;
        out[5] = lossobj; out[6] = losscls; out[7] = lossiou; out[8] = r50; out[9] = r75;
    }
}

extern "C" void kernel_launch(void* const* d_in, const int* in_sizes, int n_in,
                              void* d_out, int out_size, void* d_ws, size_t ws_size,
                              hipStream_t stream) {
    const float* pred = (const float*)d_in[0];
    const float* gtp  = (const float*)d_in[1];
    float* out = (float*)d_out;
    float* ws  = (float*)d_ws;
    int ntot = in_sizes[0];          // 22,056,960
    int G    = in_sizes[1] / 6;      // 200

    float* cls_part = ws;
    float* obj_part = ws + NBLK;
    float* sp_part  = ws + 2 * NBLK;
    int sblk = (3 * G + 3) / 4;      // 150

    int n4 = ntot / 4;
    yolo_main<<<NBLK, 256, 0, stream>>>((const float4*)pred, n4, pred, gtp, G,
                                        cls_part, obj_part, sp_part, sblk);
    finalize_k<<<1, 256, 0, stream>>>(cls_part, obj_part, sp_part, sblk, out);
}

// Round 11
// 24.203 us; speedup vs baseline: 1.0865x; 1.0865x over previous
//
#include <hip/hip_runtime.h>

// anchors[MASK] / stride:  [[1.25,1.625],[2.0,3.75],[4.125,2.875]]
__constant__ float c_aw[3] = {1.25f, 2.0f, 4.125f};
__constant__ float c_ah[3] = {1.625f, 3.75f, 2.875f};

#define LOG2E 1.4426950408889634f
#define LN2   0.6931471805599453f
#define NBLK  2048
#define SPBLK 150                       // sparse-only blocks (= sblk)
#define NDB   (NBLK - SPBLK)            // 1898 dense blocks
#define MAXG  256

typedef float floatx4 __attribute__((ext_vector_type(4)));  // nt-load compatible

// softplus(v) = log(1+e^v), via native v_exp_f32 / v_log_f32 (both ~1 ulp)
__device__ __forceinline__ float softplus_fast(float v) {
    float a = fabsf(v);
    float e = __builtin_amdgcn_exp2f(-a * LOG2E);     // e^{-|v|} in [0,1]
    float l = __builtin_amdgcn_logf(1.0f + e) * LN2;  // log1p(e), arg in [1,2]
    return fmaxf(v, 0.0f) + l;
}

// BCE(sigmoid(v), t) with torch-style clamp(log, -100)
__device__ __forceinline__ float bce_logit(float v, float t) {
    float l1p = fmaxf(-softplus_fast(v),  -100.0f);  // log(1-p)
    float lp  = fmaxf(-softplus_fast(-v), -100.0f);  // log(p)
    return -(t * lp + (1.0f - t) * l1p);
}

__device__ __forceinline__ float iou_box(float ax0, float ay0, float ax1, float ay1,
                                         float bx0, float by0, float bx1, float by1) {
    float ltx = fmaxf(ax0, bx0), lty = fmaxf(ay0, by0);
    float rbx = fminf(ax1, bx1), rby = fminf(ay1, by1);
    float iw = fmaxf(rbx - ltx, 0.0f), ih = fmaxf(rby - lty, 0.0f);
    float inter = iw * ih;
    float a1 = (ax1 - ax0) * (ay1 - ay0);
    float a2 = (bx1 - bx0) * (by1 - by0);
    return inter / (a1 + a2 - inter);
}

// ws layout (floats) — only per-block partial slots, all written
// unconditionally every call (poison-safe, no memset, no atomics, no fences):
// [0 .. NDB)             per-dense-block cls partials
// [NDB .. 2*NDB)         per-dense-block obj partials
// [2*NDB .. +SPBLK*11)   per-sparse-block partials (11 each)

// K1: blocks 0..SPBLK-1 = sparse-only (finish early, fully overlapped under
// the BW-saturated dense stream). Blocks SPBLK..NBLK-1 = dense-only.
// Rationale (R9): dense pass is chip-BW-bound (VALU-cut and MLP both
// neutral), so dense/CU imbalance is free — but the old layout serialized
// sparse AFTER the sparse blocks' dense share, extending the critical path.
// Dense loads are nontemporal (read-once stream; L3 flushed between replays).
__global__ void __launch_bounds__(256) yolo_main(const floatx4* __restrict__ p4, int n4,
                                                 const float* __restrict__ pred,
                                                 const float* __restrict__ gt, int G,
                                                 float* __restrict__ cls_part,
                                                 float* __restrict__ obj_part,
                                                 float* __restrict__ sp_part) {
    int tid = threadIdx.x;
    int lane = tid & 63;
    int wave = tid >> 6;

    if (blockIdx.x >= SPBLK) {
        // ---------------- dense pass ----------------
        // Flat: idx = cell*85 + f -> f = idx % 85. Sum min(softplus,100) in
        // log2 domain; obj (f==4) and skip-set (f<5) classified on the cell
        // phase r with compile-time thresholds; cls = total - skip.
        int bd = blockIdx.x - SPBLK;                    // 0..NDB-1
        float atot = 0.0f, askip = 0.0f, aobj = 0.0f;   // log2 units
        const float C100 = 100.0f * LOG2E;
        int i = bd * 256 + tid;
        int r = (i * 4) % 85;
        const int stride = NDB * 256;                   // 485888 float4
        for (; i < n4; i += stride) {
            floatx4 v = __builtin_nontemporal_load(&p4[i]);
            float vs[4] = {v.x, v.y, v.z, v.w};
            float s[4];
#pragma unroll
            for (int j = 0; j < 4; ++j) {
                float t = __builtin_amdgcn_exp2f(vs[j] * LOG2E);
                s[j] = fminf(__builtin_amdgcn_logf(1.0f + t), C100);
                atot += s[j];
            }
            askip += (r < 5) ? s[0] : 0.0f;
            askip += (r < 4 || r >= 84) ? s[1] : 0.0f;
            askip += (r < 3 || r >= 83) ? s[2] : 0.0f;
            askip += (r < 2 || r >= 82) ? s[3] : 0.0f;
            aobj  += (r == 4) ? s[0] : 0.0f;
            aobj  += (r == 3) ? s[1] : 0.0f;
            aobj  += (r == 2) ? s[2] : 0.0f;
            aobj  += (r == 1) ? s[3] : 0.0f;
            r += 27;                   // (4*NDB*256) % 85 == 27
            r = (r >= 85) ? r - 85 : r;
        }
        float acls = (atot - askip) * LN2;          // back to natural log
        float aob  = aobj * LN2;
#pragma unroll
        for (int off = 32; off > 0; off >>= 1) {
            acls += __shfl_down(acls, off);
            aob  += __shfl_down(aob, off);
        }
        __shared__ float rc[4], ro[4];
        if (lane == 0) { rc[wave] = acls; ro[wave] = aob; }
        __syncthreads();
        if (tid == 0) {
            cls_part[bd] = rc[0] + rc[1] + rc[2] + rc[3];
            obj_part[bd] = ro[0] + ro[1] + ro[2] + ro[3];
        }
        return;
    }

    // ---------------- sparse pass (blocks < SPBLK) ----------------
    __shared__ float s_cx[MAXG], s_cy[MAXG], s_gw[MAXG], s_gh[MAXG], s_sc[MAXG];
    __shared__ int s_ix[MAXG], s_iy[MAXG], s_bs[MAXG], s_lab[MAXG];
    __shared__ unsigned char s_m[3 * MAXG];
    __shared__ float acc[11];
    if (tid < 11) acc[tid] = 0.0f;

    for (int g = tid; g < G; g += blockDim.x) {
        float lab = gt[g * 6 + 0];
        float cx  = gt[g * 6 + 1] * 52.0f;
        float cy  = gt[g * 6 + 2] * 52.0f;
        float gw  = gt[g * 6 + 3] * 52.0f;
        float gh  = gt[g * 6 + 4] * 52.0f;
        float bn  = gt[g * 6 + 5];
        s_cx[g] = cx; s_cy[g] = cy; s_gw[g] = gw; s_gh[g] = gh;
        s_ix[g] = (int)floorf(cx); s_iy[g] = (int)floorf(cy);
        s_bs[g] = (int)bn; s_lab[g] = (int)lab;
        s_sc[g] = 2.0f - (gw * 8.0f) * (gh * 8.0f) / 173056.0f;
    }
    __syncthreads();

    for (int t = tid; t < 3 * G; t += blockDim.x) {
        int g = t / 3, a = t % 3;
        float cx = s_cx[g], cy = s_cy[g], gw = s_gw[g], gh = s_gh[g];
        float aw = c_aw[a], ah = c_ah[a];
        float iou = iou_box(cx - gw * 0.5f, cy - gh * 0.5f,
                            cx + gw * 0.5f, cy + gh * 0.5f,
                            cx - aw * 0.5f, cy - ah * 0.5f,
                            cx + aw * 0.5f, cy + ah * 0.5f);
        s_m[t] = (iou > 0.3f) ? 1 : 0;
    }
    __syncthreads();

    int t = blockIdx.x * 4 + wave;       // pair index (wave-uniform)
    bool active = (t < 3 * G) && s_m[t];
    if (active) {
        int g = t / 3, a = t % 3;
        int ix = s_ix[g], iy = s_iy[g], bs = s_bs[g], lab = s_lab[g];
        // wave-parallel "any later gt writing same cell (/same label)?"
        bool ohit = false, rhit = false;
        for (int g2 = g + 1 + lane; g2 < G; g2 += 64) {
            if (s_m[g2 * 3 + a] && s_bs[g2] == bs && s_ix[g2] == ix && s_iy[g2] == iy) {
                ohit = true;
                if (s_lab[g2] == lab) rhit = true;
            }
        }
        bool owner = !__any(ohit);
        bool rep   = !__any(rhit);

        if (lane == 0) {
            float cx = s_cx[g], cy = s_cy[g], gw = s_gw[g], gh = s_gh[g], sc = s_sc[g];
            float aw = c_aw[a], ah = c_ah[a];
            int base = ((bs * 3 + a) * 2704 + ix * 52 + iy) * 85;
            float v0 = pred[base + 0], v1 = pred[base + 1], v2 = pred[base + 2];
            float v3 = pred[base + 3], v4 = pred[base + 4];
            // reference quirk: predx adds the H-axis grid (iy), predy adds ix
            float px = 1.0f / (1.0f + __builtin_amdgcn_exp2f(-v0 * LOG2E)) + (float)iy;
            float py = 1.0f / (1.0f + __builtin_amdgcn_exp2f(-v1 * LOG2E)) + (float)ix;
            float pw = __builtin_amdgcn_exp2f(v2 * LOG2E) * aw;
            float ph = __builtin_amdgcn_exp2f(v3 * LOG2E) * ah;
            float pg = iou_box(cx - gw * 0.5f, cy - gh * 0.5f,
                               cx + gw * 0.5f, cy + gh * 0.5f,
                               px - pw * 0.5f, py - ph * 0.5f,
                               px + pw * 0.5f, py + ph * 0.5f);
            atomicAdd(&acc[7], 1.0f);                 // nmask
            atomicAdd(&acc[6], (1.0f - pg) * sc);     // iou loss sum
            if (pg > 0.5f)  atomicAdd(&acc[8], 1.0f);
            if (pg > 0.75f) atomicAdd(&acc[9], 1.0f);
            if (owner) {  // last-write-wins owner of cell (bs,a,ix,iy)
                float tx = cx - floorf(cx);
                float ty = cy - floorf(cy);
                float ow = __builtin_amdgcn_logf(gw / aw) * LN2;
                float oh = __builtin_amdgcn_logf(gh / ah) * LN2;
                atomicAdd(&acc[0], sc * bce_logit(v0, tx));
                atomicAdd(&acc[1], sc * bce_logit(v1, ty));
                float dw = v2 * sc - ow * sc;
                float dh = v3 * sc - oh * sc;
                atomicAdd(&acc[2], dw * dw);
                atomicAdd(&acc[3], dh * dh);
                atomicAdd(&acc[4], bce_logit(v4, 1.0f) - bce_logit(v4, 0.0f));
            }
            if (rep) {   // unique (cell,label) representative
                float vc = pred[base + 5 + lab];
                atomicAdd(&acc[5], bce_logit(vc, 1.0f) - bce_logit(vc, 0.0f));
                atomicAdd(&acc[10], 1.0f);
            }
        }
    }
    __syncthreads();
    if (tid < 11) sp_part[blockIdx.x * 11 + tid] = acc[tid];
}

// K2: sums all partials and composes the 10 outputs (1 block).
__global__ void __launch_bounds__(256) finalize_k(const float* __restrict__ cls_part,
                                                  const float* __restrict__ obj_part,
                                                  const float* __restrict__ sp_part,
                                                  float* __restrict__ out) {
    float c = 0.0f, o = 0.0f;
    for (int i = threadIdx.x; i < NDB; i += 256) {
        c += cls_part[i];
        o += obj_part[i];
    }
    float a[11];
#pragma unroll
    for (int k = 0; k < 11; ++k) a[k] = 0.0f;
    for (int b = threadIdx.x; b < SPBLK; b += 256) {
#pragma unroll
        for (int k = 0; k < 11; ++k) a[k] += sp_part[b * 11 + k];
    }
#pragma unroll
    for (int off = 32; off > 0; off >>= 1) {
        c += __shfl_down(c, off);
        o += __shfl_down(o, off);
#pragma unroll
        for (int k = 0; k < 11; ++k) a[k] += __shfl_down(a[k], off);
    }
    __shared__ float red[4][13];
    int wave = threadIdx.x >> 6, lane = threadIdx.x & 63;
    if (lane == 0) {
        red[wave][0] = c; red[wave][1] = o;
#pragma unroll
        for (int k = 0; k < 11; ++k) red[wave][2 + k] = a[k];
    }
    __syncthreads();
    if (threadIdx.x == 0) {
        float s[13];
#pragma unroll
        for (int k = 0; k < 13; ++k)
            s[k] = red[0][k] + red[1][k] + red[2][k] + red[3][k];
        float cls_base = s[0], obj_base = s[1];
        float SX = s[2], SY = s[3], SW = s[4], SH = s[5], OBJC = s[6], CLSC = s[7];
        float IOUS = s[8], NMASK = s[9], R50 = s[10], R75 = s[11], DEN = s[12];
        const float NCELL = 259584.0f;      // 32*3*52*52
        const float NCLSE = 20766720.0f;    // *80
        float lossx = SX / NCELL;
        float lossy = SY / NCELL;
        float lossw = SW / NCELL;
        float lossh = SH / NCELL;
        float lossobj = (obj_base + OBJC) / NCELL;
        float losscls = (cls_base + CLSC) / NCLSE;
        float lossiou = (NMASK > 0.0f) ? (IOUS / fmaxf(NMASK, 1.0f)) : 0.0f;
        float denom = DEN + 1e-10f;
        float r50 = R50 / denom;
        float r75 = R75 / denom;
        float loss = lossx + lossy + lossw + lossh + lossobj + losscls + lossiou;
        out[0] = loss;  out[1] = lossx;   out[2] = lossy;   out[3] = lossw; out[4] = lossh;
        out[5] = lossobj; out[6] = losscls; out[7] = lossiou; out[8] = r50; out[9] = r75;
    }
}

extern "C" void kernel_launch(void* const* d_in, const int* in_sizes, int n_in,
                              void* d_out, int out_size, void* d_ws, size_t ws_size,
                              hipStream_t stream) {
    const float* pred = (const float*)d_in[0];
    const float* gtp  = (const float*)d_in[1];
    float* out = (float*)d_out;
    float* ws  = (float*)d_ws;
    int ntot = in_sizes[0];          // 22,056,960
    int G    = in_sizes[1] / 6;      // 200

    float* cls_part = ws;
    float* obj_part = ws + NDB;
    float* sp_part  = ws + 2 * NDB;

    int n4 = ntot / 4;
    yolo_main<<<NBLK, 256, 0, stream>>>((const floatx4*)pred, n4, pred, gtp, G,
                                        cls_part, obj_part, sp_part);
    finalize_k<<<1, 256, 0, stream>>>(cls_part, obj_part, sp_part, out);
}